// Round 12
// baseline (9017.238 us; speedup 1.0000x reference)
//
#include <hip/hip_runtime.h>
#include <hip/hip_bf16.h>
#include <math.h>

#define Bb 64
#define Tt 512
#define Dd 1024
#define Uu 1024
#define NWGS 256     // step-kernel WGs: one per CU, WG j owns u in [j*4, j*4+4)
#define PLD 18       // LDS partial row stride (floats)

typedef __attribute__((ext_vector_type(8))) short bf16x8;
typedef __attribute__((ext_vector_type(4))) float f32x4;

// ---- one-time prep ---------------------------------------------------------

__global__ void cast_x_bf16(const float* __restrict__ in, __hip_bfloat16* __restrict__ out, int n4) {
  int i = blockIdx.x * blockDim.x + threadIdx.x;
  int stride = gridDim.x * blockDim.x;
  for (; i < n4; i += stride) {
    float4 v = reinterpret_cast<const float4*>(in)[i];
    __hip_bfloat16* o = out + 4 * (size_t)i;
    o[0] = __float2bfloat16(v.x);
    o[1] = __float2bfloat16(v.y);
    o[2] = __float2bfloat16(v.z);
    o[3] = __float2bfloat16(v.w);
  }
}

// fp32 [K][4096] -> pWT[(j*16 + pc)*2048 + koff + k] bf16,
// col = g*1024 + j*4 + uu  ->  j=(col&1023)>>2, pc = g*4 + uu.
__global__ void pack_w(const float* __restrict__ in, __hip_bfloat16* __restrict__ pWT, int koff) {
  __shared__ float tile[32][33];
  int n0 = blockIdx.x * 32, k0 = blockIdx.y * 32;
  int tx = threadIdx.x, ty = threadIdx.y;
#pragma unroll
  for (int p = 0; p < 4; ++p) {
    int r = ty + p * 8;
    tile[r][tx] = in[(size_t)(k0 + r) * (4 * Uu) + n0 + tx];
  }
  __syncthreads();
#pragma unroll
  for (int p = 0; p < 4; ++p) {
    int r = ty + p * 8;
    int col = n0 + r;
    int j = (col & (Uu - 1)) >> 2;
    int pc = (col >> 10) * 4 + (col & 3);
    pWT[((size_t)(j * 16 + pc)) * 2048 + koff + k0 + tx] = __float2bfloat16(tile[tx][r]);
  }
}

// ---- ladder macros (proven: counted vmcnt, 2-deep, no spill) ----------------

#define WAITV(n)                                             \
  do {                                                       \
    asm volatile("s_waitcnt vmcnt(" #n ")" ::: "memory");    \
    __builtin_amdgcn_sched_barrier(0);                       \
  } while (0)

// x batch: 4 A (bf16 16B) + 1 B (bf16 16B)
#define XI(S, kk)                                                              \
  {                                                                            \
    _Pragma("unroll") for (int mt = 0; mt < 4; ++mt) {                         \
      asm volatile("global_load_dwordx4 %0, %1, off offset:%2"                 \
                   : "=&v"(S[mt]) : "v"(xaddr[mt]), "i"((kk) * 64)             \
                   : "memory");                                                \
    }                                                                          \
    asm volatile("global_load_dwordx4 %0, %1, off offset:%2"                   \
                 : "=&v"(S[4]) : "v"(baddr), "i"((kk) * 64) : "memory");       \
  }

#define XC(S)                                                                  \
  {                                                                            \
    bf16x8 wb = __builtin_bit_cast(bf16x8, S[4]);                              \
    _Pragma("unroll") for (int mt = 0; mt < 4; ++mt)                           \
      acc[mt] = __builtin_amdgcn_mfma_f32_16x16x32_bf16(                       \
          __builtin_bit_cast(bf16x8, S[mt]), wb, acc[mt], 0, 0, 0);            \
  }

// h batch: 8 A (fp32, 2x16B per mt) + 1 B
#define HI(S, kk)                                                              \
  {                                                                            \
    _Pragma("unroll") for (int mt = 0; mt < 4; ++mt) {                         \
      asm volatile("global_load_dwordx4 %0, %2, off offset:%3\n\t"             \
                   "global_load_dwordx4 %1, %2, off offset:%4"                 \
                   : "=&v"(S[mt * 2]), "=&v"(S[mt * 2 + 1])                    \
                   : "v"(haddr[mt]), "i"((kk) * 128), "i"((kk) * 128 + 16)     \
                   : "memory");                                                \
    }                                                                          \
    asm volatile("global_load_dwordx4 %0, %1, off offset:%2"                   \
                 : "=&v"(S[8]) : "v"(baddr), "i"((kk) * 64) : "memory");       \
  }

#define HC(S)                                                                  \
  {                                                                            \
    bf16x8 wb = __builtin_bit_cast(bf16x8, S[8]);                              \
    _Pragma("unroll") for (int mt = 0; mt < 4; ++mt) {                         \
      f32x4 fa = S[mt * 2], fb = S[mt * 2 + 1];                                \
      union { bf16x8 v; __hip_bfloat16 e[8]; } u;                              \
      u.e[0] = __float2bfloat16(fa[0]); u.e[1] = __float2bfloat16(fa[1]);      \
      u.e[2] = __float2bfloat16(fa[2]); u.e[3] = __float2bfloat16(fa[3]);      \
      u.e[4] = __float2bfloat16(fb[0]); u.e[5] = __float2bfloat16(fb[1]);      \
      u.e[6] = __float2bfloat16(fb[2]); u.e[7] = __float2bfloat16(fb[3]);      \
      acc[mt] = __builtin_amdgcn_mfma_f32_16x16x32_bf16(u.v, wb, acc[mt], 0, 0, 0); \
    }                                                                          \
  }

__device__ __forceinline__ float sigm(float v) { return 1.f / (1.f + __expf(-v)); }

// ---- one LSTM step -----------------------------------------------------------
// 256 WGs x 512 thr. WG j owns u in [j*4, j*4+4) -> 16 cols (4 gates x 4 u).
// Waves 0..3: x_t @ Wx, K-slice wv*256.  Waves 4..7: h(t) @ Wh, K-slice (wv-4)*256.
// h(t) comes from out[:, t-1, :] (plain cached loads — kernel-boundary coherence).
// Weights: packed bf16, each element read exactly once per step (L3-resident).
// Epilogue: sum 8 partials + bias, gates, c (ws), h -> out[:, t, :].
__launch_bounds__(512)
__global__ void lstm_step(const __hip_bfloat16* __restrict__ xb,
                          const __hip_bfloat16* __restrict__ pWT,
                          const float* __restrict__ bias,
                          const float* __restrict__ h0,
                          const float* __restrict__ c0,
                          float* __restrict__ cws,
                          float* __restrict__ out,
                          int t) {
  __shared__ float part[8][Bb][PLD];
  const int tid = threadIdx.x;
  const int wv = tid >> 6;
  const int lane = tid & 63;
  const int l15 = lane & 15;
  const int lk = lane >> 4;
  const int j = blockIdx.x;

  const bool isH = wv >= 4;
  const int ks = isH ? (wv - 4) : wv;

  unsigned long long baddr =
      (unsigned long long)(pWT + ((size_t)j * 16 + l15) * 2048 + (isH ? Dd : 0) + ks * 256) +
      (unsigned long long)lk * 16;

  f32x4 acc[4];
#pragma unroll
  for (int mt = 0; mt < 4; ++mt) acc[mt] = (f32x4){0.f, 0.f, 0.f, 0.f};

  if (!isH) {
    unsigned long long xaddr[4];
#pragma unroll
    for (int mt = 0; mt < 4; ++mt)
      xaddr[mt] = (unsigned long long)(xb + ((size_t)(mt * 16 + l15) * Tt + t) * Dd + ks * 256) +
                  (unsigned long long)lk * 16;
    f32x4 s0[5], s1[5];
    XI(s0, 0); XI(s1, 1);
    WAITV(5); XC(s0); XI(s0, 2);
    WAITV(5); XC(s1); XI(s1, 3);
    WAITV(5); XC(s0); XI(s0, 4);
    WAITV(5); XC(s1); XI(s1, 5);
    WAITV(5); XC(s0); XI(s0, 6);
    WAITV(5); XC(s1); XI(s1, 7);
    WAITV(5); XC(s0);
    WAITV(0); XC(s1);
  } else {
    const float* hsrc = (t == 0) ? h0 : (out + (size_t)(t - 1) * Uu);
    const size_t hstr = (t == 0) ? (size_t)Uu : (size_t)Tt * Uu;
    unsigned long long haddr[4];
#pragma unroll
    for (int mt = 0; mt < 4; ++mt)
      haddr[mt] = (unsigned long long)(hsrc + (size_t)(mt * 16 + l15) * hstr + ks * 256) +
                  (unsigned long long)lk * 32;
    f32x4 s0[9], s1[9];
    HI(s0, 0); HI(s1, 1);
    WAITV(9); HC(s0); HI(s0, 2);
    WAITV(9); HC(s1); HI(s1, 3);
    WAITV(9); HC(s0); HI(s0, 4);
    WAITV(9); HC(s1); HI(s1, 5);
    WAITV(9); HC(s0); HI(s0, 6);
    WAITV(9); HC(s1); HI(s1, 7);
    WAITV(9); HC(s0);
    WAITV(0); HC(s1);
  }

  // C/D layout: col = lane&15, row = (lane>>4)*4 + q  [m89/m91]
#pragma unroll
  for (int mt = 0; mt < 4; ++mt)
#pragma unroll
    for (int q = 0; q < 4; ++q)
      part[wv][mt * 16 + lk * 4 + q][l15] = acc[mt][q];
  __syncthreads();

  // ---- epilogue: 256 threads, one (b,u) each
  if (tid < Bb * 4) {
    const int b = tid >> 2;
    const int uu = tid & 3;
    const int u = j * 4 + uu;
    float z[4];
#pragma unroll
    for (int g = 0; g < 4; ++g) {
      const int pc = g * 4 + uu;
      float s = part[0][b][pc];
#pragma unroll
      for (int w = 1; w < 8; ++w) s += part[w][b][pc];
      z[g] = s + bias[g * Uu + u];
    }
    const int ci = b * Uu + u;
    float cp = (t == 0) ? c0[ci] : cws[ci];
    float ig = sigm(z[0]);
    float fg = sigm(z[1]);
    float gg = tanhf(z[2]);
    float og = sigm(z[3]);
    float cn = fg * cp + ig * gg;
    cws[ci] = cn;
    out[((size_t)b * Tt + t) * Uu + u] = og * tanhf(cn);
  }
}

// ---- launch ------------------------------------------------------------------

extern "C" void kernel_launch(void* const* d_in, const int* in_sizes, int n_in,
                              void* d_out, int out_size, void* d_ws, size_t ws_size,
                              hipStream_t stream) {
  const float* x = (const float*)d_in[0];
  const float* h0 = (const float*)d_in[1];
  const float* c0 = (const float*)d_in[2];
  const float* Wx = (const float*)d_in[3];
  const float* Wh = (const float*)d_in[4];
  const float* bias = (const float*)d_in[5];
  float* out = (float*)d_out;

  char* ws = (char*)d_ws;
  size_t off = 0;
  __hip_bfloat16* xb = (__hip_bfloat16*)(ws + off);  off += (size_t)Bb * Tt * Dd * 2;  // 64 MB
  __hip_bfloat16* pWT = (__hip_bfloat16*)(ws + off); off += (size_t)4096 * 2048 * 2;   // 16.8 MB
  float* cws = (float*)(ws + off);                   off += (size_t)Bb * Uu * 4;       // 256 KB

  cast_x_bf16<<<4096, 256, 0, stream>>>(x, xb, Bb * Tt * Dd / 4);
  pack_w<<<dim3(4 * Uu / 32, Dd / 32), dim3(32, 8), 0, stream>>>(Wx, pWT, 0);
  pack_w<<<dim3(4 * Uu / 32, Uu / 32), dim3(32, 8), 0, stream>>>(Wh, pWT, Dd);

  for (int t = 0; t < Tt; ++t)
    lstm_step<<<NWGS, 512, 0, stream>>>(xb, pWT, bias, h0, c0, cws, out, t);
}